// Round 8
// baseline (859.967 us; speedup 1.0000x reference)
//
#include <hip/hip_runtime.h>
#include <hip/hip_fp16.h>

#define N_NODES 250000
#define N_EDGES 4000000
#define DIM 64

// flat bucketed CSR build: 3907 buckets x 64 rows, fixed-capacity windows
#define RB_BITS 6
#define ROWS_PER_B 64
#define NB 3907           // ceil(250000/64)
#define WCAP 1536         // words per bucket window (mean fill 1024, +16 sigma)

// ---------------- workspace layout (bytes) ----------------
// [0        , 1'000'000)   deg       int[250000]
// [1'000'000, 2'000'000)   row_ptr   int[250000]   (word index into cbuf)
// [2'000'000, 3'000'000)   dis       float[250000]
// [3'000'000, 3'015'628)   bucket_cursor int[3907]
// [4'000'000, 28'004'608)  ebuf: bucketed edges, 3907 x 1536 words
// [29'000'000, 53'004'608) cbuf: csr cols, 3907 x 1536 words
// [54'000'000, 86'000'000) fp16 feat bufA  half[250000*64]
// [86'000'000,118'000'000) fp16 feat bufB  half[250000*64]
#define WS_FP16_NEED 118000000ull

typedef float f32x4v __attribute__((ext_vector_type(4)));

__device__ __forceinline__ unsigned pack2h(float a, float b) {
    unsigned ua = (unsigned)__half_as_ushort(__float2half_rn(a));
    unsigned ub = (unsigned)__half_as_ushort(__float2half_rn(b));
    return ua | (ub << 16);
}
__device__ __forceinline__ float2 unpack2h(unsigned u) {
    float a = __half2float(__ushort_as_half((unsigned short)(u & 0xffffu)));
    float b = __half2float(__ushort_as_half((unsigned short)(u >> 16)));
    return make_float2(a, b);
}
__device__ __forceinline__ void nt_store4(float4 v, float* p) {
    f32x4v vv = {v.x, v.y, v.z, v.w};
    __builtin_nontemporal_store(vv, (f32x4v*)p);
}

// window cursors: bcur[b] = b*WCAP (word offset of bucket b's window in ebuf)
__global__ __launch_bounds__(256) void init_cursors(int* __restrict__ bcur) {
    int t = blockIdx.x * 256 + threadIdx.x;
    if (t < NB) bcur[t] = t * WCAP;
}

// P1: pure global-atomic scatter into per-bucket windows. No LDS, no scan.
// Packs (rlow<<18)|col into one uint32 (col < 2^18).
__global__ __launch_bounds__(256) void scatter_edges(
        const int* __restrict__ row, const int* __restrict__ col,
        int* __restrict__ bcur, unsigned int* __restrict__ ebuf) {
    int e4 = blockIdx.x * 256 + threadIdx.x;
    if (e4 >= N_EDGES / 4) return;
    int4 r = ((const int4*)row)[e4];
    int4 c = ((const int4*)col)[e4];
    int rr[4] = {r.x, r.y, r.z, r.w};
    int cc[4] = {c.x, c.y, c.z, c.w};
#pragma unroll
    for (int u = 0; u < 4; ++u) {
        int b = rr[u] >> RB_BITS;
        int p = atomicAdd(&bcur[b], 1);
        if (p < (b + 1) * WCAP)   // overflow guard (P ~ 0 at +16 sigma)
            ebuf[p] = ((unsigned)(rr[u] & (ROWS_PER_B - 1)) << 18) | (unsigned)cc[u];
    }
}

// P2: one light block per bucket (64 rows, mean 1024 edges). LDS 64-counter
// histogram + 6-step scan -> deg/row_ptr/dis, then scatter cols into the
// bucket's 6KB CSR window (L2-hot).
__global__ __launch_bounds__(256) void build_csr64(
        const int* __restrict__ bcur, const unsigned int* __restrict__ ebuf,
        unsigned int* __restrict__ cbuf,
        int* __restrict__ deg, int* __restrict__ row_ptr, float* __restrict__ dis) {
    __shared__ int histo[ROWS_PER_B];
    __shared__ int base[ROWS_PER_B];
    int b = blockIdx.x;
    int wstart = b * WCAP;
    int nb = bcur[b] - wstart; if (nb > WCAP) nb = WCAP;
    const unsigned int* ewin = ebuf + wstart;
    int t = threadIdx.x;
    if (t < ROWS_PER_B) histo[t] = 0;
    __syncthreads();
    for (int s = t; s < nb; s += 256)
        atomicAdd(&histo[ewin[s] >> 18], 1);
    __syncthreads();
    if (t < ROWS_PER_B) base[t] = histo[t];
    __syncthreads();
    for (int off = 1; off < ROWS_PER_B; off <<= 1) {
        int u = 0;
        if (t < ROWS_PER_B && t >= off) u = base[t - off];
        __syncthreads();
        if (t < ROWS_PER_B) base[t] += u;
        __syncthreads();
    }
    if (t < ROWS_PER_B) {
        int hv = histo[t];
        int ex = base[t] - hv;
        base[t] = ex;                    // base[] doubles as scatter cursor
        int node = (b << RB_BITS) + t;
        if (node < N_NODES) {
            deg[node] = hv;
            row_ptr[node] = wstart + ex; // word index into cbuf
            dis[node] = rsqrtf((float)(hv + 1));
        }
    }
    __syncthreads();
    for (int s = t; s < nb; s += 256) {
        unsigned int w = ewin[s];
        int p = atomicAdd(&base[w >> 18], 1);
        cbuf[wstart + p] = w & 0x3FFFFu;
    }
}

// emb f32 -> fp16 copy. Each thread: 4 floats -> 4 halves (8B).
__global__ __launch_bounds__(256) void f32_to_f16(const float* __restrict__ in,
                                                  unsigned int* __restrict__ outh) {
    int i = blockIdx.x * blockDim.x + threadIdx.x;   // float4 index
    if (i < N_NODES * (DIM / 4)) {
        float4 v = ((const float4*)in)[i];
        uint2 pk;
        pk.x = pack2h(v.x, v.y);
        pk.y = pack2h(v.z, v.w);
        ((uint2*)outh)[i] = pk;
    }
}

// fp16-gather spmm: 16 lanes per row, lane = 4 dims (8B load), 4 rows/wave.
// f32 accumulate; nontemporal f32 stores (streaming, never re-read) keep
// L2/L3 free for the 32MB fp16 gather table. fp16 copy stays cached.
__global__ __launch_bounds__(256) void spmm_h(const int* __restrict__ row_ptr,
                                              const int* __restrict__ deg,
                                              const unsigned int* __restrict__ csr_col,
                                              const float* __restrict__ dis,
                                              const unsigned int* __restrict__ fin_h,  // [N,64] half
                                              float* __restrict__ fout, int out_stride4, int out_off,
                                              unsigned int* __restrict__ fout_h,       // fp16 copy or null
                                              float* __restrict__ fout2) {
    int lane = threadIdx.x & 63;
    int lq   = lane & 15;
    int qb   = lane & 48;
    int r    = blockIdx.x * 16 + (threadIdx.x >> 4);
    if (r >= N_NODES) return;

    const uint2* fin2 = (const uint2*)fin_h;   // 8B granules, row = 16 granules
    float dr = dis[r];
    uint2 sh = fin2[(size_t)r * 16 + lq];
    float2 s0 = unpack2h(sh.x), s1 = unpack2h(sh.y);
    float4 acc;
    acc.x = dr * s0.x; acc.y = dr * s0.y;
    acc.z = dr * s1.x; acc.w = dr * s1.y;

    int start = row_ptr[r];
    int cnt   = deg[r];
    for (int base = 0; base < cnt; base += 16) {
        int m = cnt - base; if (m > 16) m = 16;
        int cl = 0; float wl = 0.f;
        if (lq < m) {
            cl = (int)csr_col[start + base + lq];
            wl = dis[cl];
        }
        int m8 = (m + 7) & ~7;
        for (int j = 0; j < m8; j += 8) {
            int c[8]; float w[8]; uint2 f[8];
#pragma unroll
            for (int u = 0; u < 8; ++u) {
                c[u] = __shfl(cl, qb + j + u);
                w[u] = __shfl(wl, qb + j + u);
                f[u] = fin2[(size_t)c[u] * 16 + lq];
            }
#pragma unroll
            for (int u = 0; u < 8; ++u) {
                float2 a = unpack2h(f[u].x), bb = unpack2h(f[u].y);
                acc.x += w[u] * a.x;
                acc.y += w[u] * a.y;
                acc.z += w[u] * bb.x;
                acc.w += w[u] * bb.y;
            }
        }
    }
    float4 v;
    v.x = dr * acc.x; v.y = dr * acc.y;
    v.z = dr * acc.z; v.w = dr * acc.w;
    nt_store4(v, fout + out_off + (size_t)r * out_stride4 * 4 + lq * 4);
    if (fout_h) {
        uint2 pk;
        pk.x = pack2h(v.x, v.y);
        pk.y = pack2h(v.z, v.w);
        ((uint2*)fout_h)[(size_t)r * 16 + lq] = pk;
    }
    if (fout2) nt_store4(v, fout2 + (size_t)r * 64 + lq * 4);
}

// f32-gather spmm (fallback when workspace too small for fp16 buffers).
__global__ __launch_bounds__(256) void spmm(const int* __restrict__ row_ptr,
                                            const int* __restrict__ deg,
                                            const unsigned int* __restrict__ csr_col,
                                            const float* __restrict__ dis,
                                            const float* __restrict__ fin, int in_stride4, int in_off,
                                            float* __restrict__ fout, int out_stride4, int out_off,
                                            float* __restrict__ fout2) {
    int lane = threadIdx.x & 63;
    int lq   = lane & 15;
    int qb   = lane & 48;
    int r    = blockIdx.x * 16 + (threadIdx.x >> 4);
    if (r >= N_NODES) return;

    const float4* fin4 = (const float4*)(fin + in_off);
    float dr = dis[r];
    float4 self = fin4[(size_t)r * in_stride4 + lq];
    float4 acc;
    acc.x = dr * self.x; acc.y = dr * self.y;
    acc.z = dr * self.z; acc.w = dr * self.w;

    int start = row_ptr[r];
    int cnt   = deg[r];
    for (int base = 0; base < cnt; base += 16) {
        int m = cnt - base; if (m > 16) m = 16;
        int cl = 0; float wl = 0.f;
        if (lq < m) {
            cl = (int)csr_col[start + base + lq];
            wl = dis[cl];
        }
        int m4 = (m + 3) & ~3;
        for (int j = 0; j < m4; j += 4) {
            int c[4]; float w[4]; float4 f[4];
#pragma unroll
            for (int u = 0; u < 4; ++u) {
                c[u] = __shfl(cl, qb + j + u);
                w[u] = __shfl(wl, qb + j + u);
                f[u] = fin4[(size_t)c[u] * in_stride4 + lq];
            }
#pragma unroll
            for (int u = 0; u < 4; ++u) {
                acc.x += w[u] * f[u].x;
                acc.y += w[u] * f[u].y;
                acc.z += w[u] * f[u].z;
                acc.w += w[u] * f[u].w;
            }
        }
    }
    float4 v;
    v.x = dr * acc.x; v.y = dr * acc.y;
    v.z = dr * acc.z; v.w = dr * acc.w;
    ((float4*)(fout + out_off))[(size_t)r * out_stride4 + lq] = v;
    if (fout2) ((float4*)fout2)[(size_t)r * 16 + lq] = v;
}

extern "C" void kernel_launch(void* const* d_in, const int* in_sizes, int n_in,
                              void* d_out, int out_size, void* d_ws, size_t ws_size,
                              hipStream_t stream) {
    const int*   ei  = (const int*)d_in[0];     // edge_index [2, 4M]
    const float* emb = (const float*)d_in[1];   // [250000, 64]
    const int* row = ei;
    const int* col = ei + N_EDGES;
    float* out = (float*)d_out;

    char* ws = (char*)d_ws;
    int*   deg      = (int*)(ws + 0);
    int*   row_ptr  = (int*)(ws + 1000000);
    float* dis      = (float*)(ws + 2000000);
    int*   bcur     = (int*)(ws + 3000000);
    unsigned int* ebuf = (unsigned int*)(ws + 4000000);   // bucketed edges
    unsigned int* cbuf = (unsigned int*)(ws + 29000000);  // csr cols (windowed)
    unsigned int* bufA = (unsigned int*)(ws + 54000000);  // half[250000*64]
    unsigned int* bufB = (unsigned int*)(ws + 86000000);

    init_cursors <<<(NB + 255) / 256, 256, 0, stream>>>(bcur);
    int sc_blocks = (N_EDGES / 4 + 255) / 256;             // 3907
    scatter_edges<<<sc_blocks, 256, 0, stream>>>(row, col, bcur, ebuf);
    build_csr64  <<<NB, 256, 0, stream>>>(bcur, ebuf, cbuf, deg, row_ptr, dis);

    // output layout: all_feat[i, slot, :] with slot0 = layer3, slot1 = layer1,
    // slot2 = layer2; then final feat (= layer3) at float offset 48'000'000.
    int spmm_blocks = N_NODES / 16 + 1;  // 15626 (guard in kernel)
    if (ws_size >= WS_FP16_NEED) {
        // fp16 gather path: emb->bufB; L1: bufB->slot1+bufA; L2: bufA->slot2+bufB;
        // L3: bufB->slot0 + final.
        int cvt_blocks = (N_NODES * (DIM / 4) + 255) / 256;
        f32_to_f16<<<cvt_blocks, 256, 0, stream>>>(emb, bufB);
        spmm_h<<<spmm_blocks, 256, 0, stream>>>(row_ptr, deg, cbuf, dis,
                                                bufB, out, 48, DIM, bufA, nullptr);
        spmm_h<<<spmm_blocks, 256, 0, stream>>>(row_ptr, deg, cbuf, dis,
                                                bufA, out, 48, 2 * DIM, bufB, nullptr);
        spmm_h<<<spmm_blocks, 256, 0, stream>>>(row_ptr, deg, cbuf, dis,
                                                bufB, out, 48, 0, nullptr, out + 48000000);
    } else {
        // f32 fallback
        spmm<<<spmm_blocks, 256, 0, stream>>>(row_ptr, deg, cbuf, dis,
                                              emb, 16, 0, out, 48, DIM, nullptr);
        spmm<<<spmm_blocks, 256, 0, stream>>>(row_ptr, deg, cbuf, dis,
                                              out, 48, DIM, out, 48, 2 * DIM, nullptr);
        spmm<<<spmm_blocks, 256, 0, stream>>>(row_ptr, deg, cbuf, dis,
                                              out, 48, 2 * DIM, out, 48, 0, out + 48000000);
    }
}

// Round 9
// 608.589 us; speedup vs baseline: 1.4130x; 1.4130x over previous
//
#include <hip/hip_runtime.h>
#include <hip/hip_fp16.h>

#define N_NODES 250000
#define N_EDGES 4000000
#define DIM 64

// bucketed CSR build: 489 buckets x 512 rows, fixed-capacity windows
#define RB_BITS 9
#define ROWS_PER_B 512
#define NB 489            // ceil(250000/512)
#define WCAP 16384        // words per bucket window (mean fill 8192, ~90 sigma)
#define P1_CHUNK 8192
#define P1_THREADS 512
#define P2_THREADS 512

// ---------------- workspace layout (bytes) ----------------
// [0        , 1'000'000)   deg       int[250000]
// [1'000'000, 2'000'000)   row_ptr   int[250000]   (word index into cbuf)
// [2'000'000, 3'000'000)   dis       float[250000]
// [3'000'000, 3'004'096)   bucket_cursor int[489]
// [4'000'000, 36'047'104)  ebuf: bucketed edges, 489 x 16384 words
// [37'000'000, 69'047'104) cbuf: csr cols, 489 x 16384 words
// [70'000'000,102'000'000) fp16 feat bufA  half[250000*64]
// [102'000'000,134'000'000) fp16 feat bufB half[250000*64]
#define WS_FP16_NEED 134000000ull

typedef float f32x4v __attribute__((ext_vector_type(4)));

__device__ __forceinline__ unsigned pack2h(float a, float b) {
    unsigned ua = (unsigned)__half_as_ushort(__float2half_rn(a));
    unsigned ub = (unsigned)__half_as_ushort(__float2half_rn(b));
    return ua | (ub << 16);
}
__device__ __forceinline__ float2 unpack2h(unsigned u) {
    float a = __half2float(__ushort_as_half((unsigned short)(u & 0xffffu)));
    float b = __half2float(__ushort_as_half((unsigned short)(u >> 16)));
    return make_float2(a, b);
}
__device__ __forceinline__ void nt_store4(float4 v, float* p) {
    f32x4v vv = {v.x, v.y, v.z, v.w};
    __builtin_nontemporal_store(vv, (f32x4v*)p);
}

// window cursors: bcur[b] = b*WCAP (word offset of bucket b's window in ebuf)
__global__ __launch_bounds__(512) void init_cursors(int* __restrict__ bcur) {
    int t = threadIdx.x;
    if (t < NB) bcur[t] = t * WCAP;
}

// P1: LDS multi-split. Each block bucket-sorts its 8192-edge chunk in LDS,
// reserves one contiguous run per bucket window (1 atomic per block-bucket),
// writes runs coalesced (XCD-local, no cross-XCD line sharing).
// Packs (rlow<<18)|col into one uint32.
__global__ __launch_bounds__(P1_THREADS) void partition_edges(
        const int* __restrict__ row, const int* __restrict__ col,
        int* __restrict__ bcur, unsigned int* __restrict__ ebuf) {
    __shared__ int histo[ROWS_PER_B];
    __shared__ int base[ROWS_PER_B];
    __shared__ int cursor[ROWS_PER_B];
    __shared__ int gbase[ROWS_PER_B];
    __shared__ unsigned int staged[P1_CHUNK];
    __shared__ unsigned short stagedB[P1_CHUNK];

    int t = threadIdx.x;
    histo[t] = 0;
    __syncthreads();

    int c4base = blockIdx.x * (P1_CHUNK / 4);
    int4 r[4], c[4];
    bool val[4];
#pragma unroll
    for (int i = 0; i < 4; ++i) {
        int e4 = c4base + i * P1_THREADS + t;
        val[i] = (e4 < N_EDGES / 4);
        if (val[i]) {
            r[i] = ((const int4*)row)[e4];
            c[i] = ((const int4*)col)[e4];
            atomicAdd(&histo[r[i].x >> RB_BITS], 1);
            atomicAdd(&histo[r[i].y >> RB_BITS], 1);
            atomicAdd(&histo[r[i].z >> RB_BITS], 1);
            atomicAdd(&histo[r[i].w >> RB_BITS], 1);
        }
    }
    __syncthreads();
    int hv = histo[t];
    base[t] = hv;
    __syncthreads();
    for (int off = 1; off < ROWS_PER_B; off <<= 1) {
        int u = (t >= off) ? base[t - off] : 0;
        __syncthreads();
        base[t] += u;
        __syncthreads();
    }
    int ex = base[t] - hv;
    base[t] = ex;
    cursor[t] = ex;
    if (t < NB && hv > 0) gbase[t] = atomicAdd(&bcur[t], hv);
    __syncthreads();
#pragma unroll
    for (int i = 0; i < 4; ++i) {
        if (val[i]) {
            int rr[4] = {r[i].x, r[i].y, r[i].z, r[i].w};
            int cc[4] = {c[i].x, c[i].y, c[i].z, c[i].w};
#pragma unroll
            for (int u = 0; u < 4; ++u) {
                int b = rr[u] >> RB_BITS;
                int pos = atomicAdd(&cursor[b], 1);
                staged[pos]  = ((unsigned)(rr[u] & (ROWS_PER_B - 1)) << 18) | (unsigned)cc[u];
                stagedB[pos] = (unsigned short)b;
            }
        }
    }
    __syncthreads();
    int cnt_total = N_EDGES - blockIdx.x * P1_CHUNK;
    if (cnt_total > P1_CHUNK) cnt_total = P1_CHUNK;
    for (int s = t; s < cnt_total; s += P1_THREADS) {
        int b = stagedB[s];
        int gpos = gbase[b] + (s - base[b]);
        ebuf[gpos] = staged[s];
    }
}

// P2: one block per bucket; two passes over the bucket's window (L2-hot on
// pass 2): histogram -> scan -> deg/row_ptr/dis, then scatter cols into the
// bucket's CSR window. No LDS staging (4KB LDS -> high occupancy).
__global__ __launch_bounds__(P2_THREADS) void build_csr(
        const int* __restrict__ bcur, const unsigned int* __restrict__ ebuf,
        unsigned int* __restrict__ cbuf,
        int* __restrict__ deg, int* __restrict__ row_ptr, float* __restrict__ dis) {
    __shared__ int histo[ROWS_PER_B];
    __shared__ int base[ROWS_PER_B];
    int b = blockIdx.x;
    int wstart = b * WCAP;
    int nb = bcur[b] - wstart;
    const unsigned int* ewin = ebuf + wstart;
    int t = threadIdx.x;
    histo[t] = 0;
    __syncthreads();
    for (int s = t; s < nb; s += P2_THREADS)
        atomicAdd(&histo[ewin[s] >> 18], 1);
    __syncthreads();
    int hv = histo[t];
    base[t] = hv;
    __syncthreads();
    for (int off = 1; off < ROWS_PER_B; off <<= 1) {
        int u = (t >= off) ? base[t - off] : 0;
        __syncthreads();
        base[t] += u;
        __syncthreads();
    }
    int ex = base[t] - hv;
    base[t] = ex;                       // base[] doubles as scatter cursor
    int node = (b << RB_BITS) + t;
    if (node < N_NODES) {
        deg[node] = hv;
        row_ptr[node] = wstart + ex;    // word index into cbuf
        dis[node] = rsqrtf((float)(hv + 1));
    }
    __syncthreads();
    for (int s = t; s < nb; s += P2_THREADS) {
        unsigned int w = ewin[s];
        int p = atomicAdd(&base[w >> 18], 1);
        cbuf[wstart + p] = w & 0x3FFFFu;
    }
}

// emb f32 -> fp16 copy. Each thread: 4 floats -> 4 halves (8B).
__global__ __launch_bounds__(256) void f32_to_f16(const float* __restrict__ in,
                                                  unsigned int* __restrict__ outh) {
    int i = blockIdx.x * blockDim.x + threadIdx.x;   // float4 index
    if (i < N_NODES * (DIM / 4)) {
        float4 v = ((const float4*)in)[i];
        uint2 pk;
        pk.x = pack2h(v.x, v.y);
        pk.y = pack2h(v.z, v.w);
        ((uint2*)outh)[i] = pk;
    }
}

// fp16-gather spmm: 16 lanes per row, lane = 4 dims (8B load), 4 rows/wave.
// f32 accumulate; nontemporal f32 stores (streaming, never re-read) keep
// L2/L3 free for the 32MB fp16 gather table. fp16 copy stays cached.
__global__ __launch_bounds__(256) void spmm_h(const int* __restrict__ row_ptr,
                                              const int* __restrict__ deg,
                                              const unsigned int* __restrict__ csr_col,
                                              const float* __restrict__ dis,
                                              const unsigned int* __restrict__ fin_h,  // [N,64] half
                                              float* __restrict__ fout, int out_stride4, int out_off,
                                              unsigned int* __restrict__ fout_h,       // fp16 copy or null
                                              float* __restrict__ fout2) {
    int lane = threadIdx.x & 63;
    int lq   = lane & 15;
    int qb   = lane & 48;
    int r    = blockIdx.x * 16 + (threadIdx.x >> 4);
    if (r >= N_NODES) return;

    const uint2* fin2 = (const uint2*)fin_h;   // 8B granules, row = 16 granules
    float dr = dis[r];
    uint2 sh = fin2[(size_t)r * 16 + lq];
    float2 s0 = unpack2h(sh.x), s1 = unpack2h(sh.y);
    float4 acc;
    acc.x = dr * s0.x; acc.y = dr * s0.y;
    acc.z = dr * s1.x; acc.w = dr * s1.y;

    int start = row_ptr[r];
    int cnt   = deg[r];
    for (int base = 0; base < cnt; base += 16) {
        int m = cnt - base; if (m > 16) m = 16;
        int cl = 0; float wl = 0.f;
        if (lq < m) {
            cl = (int)csr_col[start + base + lq];
            wl = dis[cl];
        }
        int m8 = (m + 7) & ~7;
        for (int j = 0; j < m8; j += 8) {
            int c[8]; float w[8]; uint2 f[8];
#pragma unroll
            for (int u = 0; u < 8; ++u) {
                c[u] = __shfl(cl, qb + j + u);
                w[u] = __shfl(wl, qb + j + u);
                f[u] = fin2[(size_t)c[u] * 16 + lq];
            }
#pragma unroll
            for (int u = 0; u < 8; ++u) {
                float2 a = unpack2h(f[u].x), bb = unpack2h(f[u].y);
                acc.x += w[u] * a.x;
                acc.y += w[u] * a.y;
                acc.z += w[u] * bb.x;
                acc.w += w[u] * bb.y;
            }
        }
    }
    float4 v;
    v.x = dr * acc.x; v.y = dr * acc.y;
    v.z = dr * acc.z; v.w = dr * acc.w;
    nt_store4(v, fout + out_off + (size_t)r * out_stride4 * 4 + lq * 4);
    if (fout_h) {
        uint2 pk;
        pk.x = pack2h(v.x, v.y);
        pk.y = pack2h(v.z, v.w);
        ((uint2*)fout_h)[(size_t)r * 16 + lq] = pk;
    }
    if (fout2) nt_store4(v, fout2 + (size_t)r * 64 + lq * 4);
}

// f32-gather spmm (fallback when workspace too small for fp16 buffers).
__global__ __launch_bounds__(256) void spmm(const int* __restrict__ row_ptr,
                                            const int* __restrict__ deg,
                                            const unsigned int* __restrict__ csr_col,
                                            const float* __restrict__ dis,
                                            const float* __restrict__ fin, int in_stride4, int in_off,
                                            float* __restrict__ fout, int out_stride4, int out_off,
                                            float* __restrict__ fout2) {
    int lane = threadIdx.x & 63;
    int lq   = lane & 15;
    int qb   = lane & 48;
    int r    = blockIdx.x * 16 + (threadIdx.x >> 4);
    if (r >= N_NODES) return;

    const float4* fin4 = (const float4*)(fin + in_off);
    float dr = dis[r];
    float4 self = fin4[(size_t)r * in_stride4 + lq];
    float4 acc;
    acc.x = dr * self.x; acc.y = dr * self.y;
    acc.z = dr * self.z; acc.w = dr * self.w;

    int start = row_ptr[r];
    int cnt   = deg[r];
    for (int base = 0; base < cnt; base += 16) {
        int m = cnt - base; if (m > 16) m = 16;
        int cl = 0; float wl = 0.f;
        if (lq < m) {
            cl = (int)csr_col[start + base + lq];
            wl = dis[cl];
        }
        int m4 = (m + 3) & ~3;
        for (int j = 0; j < m4; j += 4) {
            int c[4]; float w[4]; float4 f[4];
#pragma unroll
            for (int u = 0; u < 4; ++u) {
                c[u] = __shfl(cl, qb + j + u);
                w[u] = __shfl(wl, qb + j + u);
                f[u] = fin4[(size_t)c[u] * in_stride4 + lq];
            }
#pragma unroll
            for (int u = 0; u < 4; ++u) {
                acc.x += w[u] * f[u].x;
                acc.y += w[u] * f[u].y;
                acc.z += w[u] * f[u].z;
                acc.w += w[u] * f[u].w;
            }
        }
    }
    float4 v;
    v.x = dr * acc.x; v.y = dr * acc.y;
    v.z = dr * acc.z; v.w = dr * acc.w;
    ((float4*)(fout + out_off))[(size_t)r * out_stride4 + lq] = v;
    if (fout2) ((float4*)fout2)[(size_t)r * 16 + lq] = v;
}

extern "C" void kernel_launch(void* const* d_in, const int* in_sizes, int n_in,
                              void* d_out, int out_size, void* d_ws, size_t ws_size,
                              hipStream_t stream) {
    const int*   ei  = (const int*)d_in[0];     // edge_index [2, 4M]
    const float* emb = (const float*)d_in[1];   // [250000, 64]
    const int* row = ei;
    const int* col = ei + N_EDGES;
    float* out = (float*)d_out;

    char* ws = (char*)d_ws;
    int*   deg      = (int*)(ws + 0);
    int*   row_ptr  = (int*)(ws + 1000000);
    float* dis      = (float*)(ws + 2000000);
    int*   bcur     = (int*)(ws + 3000000);
    unsigned int* ebuf = (unsigned int*)(ws + 4000000);   // bucketed edges
    unsigned int* cbuf = (unsigned int*)(ws + 37000000);  // csr cols (windowed)
    unsigned int* bufA = (unsigned int*)(ws + 70000000);  // half[250000*64]
    unsigned int* bufB = (unsigned int*)(ws + 102000000);

    init_cursors   <<<1, 512, 0, stream>>>(bcur);
    int p1_blocks = (N_EDGES + P1_CHUNK - 1) / P1_CHUNK;   // 489
    partition_edges<<<p1_blocks, P1_THREADS, 0, stream>>>(row, col, bcur, ebuf);
    build_csr      <<<NB, P2_THREADS, 0, stream>>>(bcur, ebuf, cbuf, deg, row_ptr, dis);

    // output layout: all_feat[i, slot, :] with slot0 = layer3, slot1 = layer1,
    // slot2 = layer2; then final feat (= layer3) at float offset 48'000'000.
    int spmm_blocks = N_NODES / 16 + 1;  // 15626 (guard in kernel)
    if (ws_size >= WS_FP16_NEED) {
        // fp16 gather path: emb->bufB; L1: bufB->slot1+bufA; L2: bufA->slot2+bufB;
        // L3: bufB->slot0 + final.
        int cvt_blocks = (N_NODES * (DIM / 4) + 255) / 256;
        f32_to_f16<<<cvt_blocks, 256, 0, stream>>>(emb, bufB);
        spmm_h<<<spmm_blocks, 256, 0, stream>>>(row_ptr, deg, cbuf, dis,
                                                bufB, out, 48, DIM, bufA, nullptr);
        spmm_h<<<spmm_blocks, 256, 0, stream>>>(row_ptr, deg, cbuf, dis,
                                                bufA, out, 48, 2 * DIM, bufB, nullptr);
        spmm_h<<<spmm_blocks, 256, 0, stream>>>(row_ptr, deg, cbuf, dis,
                                                bufB, out, 48, 0, nullptr, out + 48000000);
    } else {
        // f32 fallback
        spmm<<<spmm_blocks, 256, 0, stream>>>(row_ptr, deg, cbuf, dis,
                                              emb, 16, 0, out, 48, DIM, nullptr);
        spmm<<<spmm_blocks, 256, 0, stream>>>(row_ptr, deg, cbuf, dis,
                                              out, 48, DIM, out, 48, 2 * DIM, nullptr);
        spmm<<<spmm_blocks, 256, 0, stream>>>(row_ptr, deg, cbuf, dis,
                                              out, 48, 2 * DIM, out, 48, 0, out + 48000000);
    }
}